// Round 5
// baseline (318.002 us; speedup 1.0000x reference)
//
#include <hip/hip_runtime.h>
#include <hip/hip_bf16.h>

// f32 in/out. Internal: bf16 MFMA. q/kv projections 1-term bf16 (W hi only);
// o-proj exact 2-term via K=512 packed [Wo_hi | Wo_lo]. Weights pre-packed in
// k_prep into the exact LDS tile image consumed by global_load_lds(16B).
// r8: RESIDENCY experiment. r6 accidentally showed 5 blocks/CU sustains
// 3.5 TB/s while our clean 3-block kernels sit at 1.1-1.7 TB/s with all pipes
// idle. k_qkv/k_oproj LDS cut 48->32 KB (single Bs + single A-image) -> 5
// blocks/CU. Per-iter: [bar-a] issue B(gll16)+A(global->reg) -> writeA ->
// [bar-b drains vmcnt] -> compute. Serial within block; overlap comes from
// 5 staggered blocks. Layouts/swizzles byte-identical to r7 (conflict-free).
// launch_bounds(256,4) only — natural VGPR ~76 <= 102 needed for 5 blk/CU.
// Accumulation order unchanged -> bit-identical (absmax 0.0078).
typedef __bf16 bf16;
typedef __bf16 bf16x8 __attribute__((ext_vector_type(8)));
typedef __bf16 bf16x4 __attribute__((ext_vector_type(4)));
typedef float  f32x4  __attribute__((ext_vector_type(4)));

#define DEVINL __device__ __forceinline__

DEVINL void gll16(const void* g, void* l) {
  __builtin_amdgcn_global_load_lds(
      (const __attribute__((address_space(1))) unsigned int*)g,
      (__attribute__((address_space(3))) unsigned int*)l, 16, 0, 0);
}

// ---------------------------------------------------------------------------
// Weight pack. Tile image (per n-tile of 128, per k-iter of 64):
//   1024 slots of 16B; slot s: h=s>>9 (k-half of 32), row=(s&511)>>2, kg=s&3
//   holds W[k0 + h*32 + kg*8 + e][n0+row] for e=0..7  (transposed+bf16).
// Both packQ and packO swizzle the kg slot: kgs = kg ^ ((row>>1)&3) so the
// consumer's ds_read_b128 at (row, lq^((lm>>1)&3)) is bank-conflict-free.
// packQ: 6 n-tiles (q:0-1, k:2-3, v:4-5) x 4 k-iters (hi only).
// packO: 2 n-tiles x 8 k-iters (iters 0-3 = Wo_hi, 4-7 = Wo_lo).
// ---------------------------------------------------------------------------
__global__ void k_prep(const float* __restrict__ Wq, const float* __restrict__ Wk,
                       const float* __restrict__ Wv, const float* __restrict__ Wo,
                       bf16* __restrict__ packQ, bf16* __restrict__ packO) {
  const int n = threadIdx.x;   // dest column 0..255
  const int k = blockIdx.x;    // source k 0..255
  const int m = blockIdx.y;    // 0:Wq 1:Wk 2:Wv 3:Wo-hi 4:Wo-lo
  const int kk = k & 63, iter4 = k >> 6;
  const int h = kk >> 5, kg = (kk >> 3) & 3, e = k & 7;
  if (m < 3) {
    const float* W = (m == 0) ? Wq : (m == 1) ? Wk : Wv;
    const bf16 v = (bf16)W[k * 256 + n];
    const int nglob = m * 256 + n;
    const int tile = nglob >> 7, row = nglob & 127;
    const int kgs = kg ^ ((row >> 1) & 3);   // bank-swizzle (matched in k_qkv)
    packQ[(size_t)((tile * 4 + iter4) * 1024 + h * 512 + row * 4 + kgs) * 8 + e] = v;
  } else {
    const float w = Wo[k * 256 + n];
    const bf16 hi = (bf16)w;
    const bf16 v = (m == 3) ? hi : (bf16)(w - (float)hi);
    const int iter = (m - 3) * 4 + iter4;
    const int tile = n >> 7, row = n & 127;
    const int kgs = kg ^ ((row >> 1) & 3);   // bank-swizzle (matched in k_oproj)
    packO[(size_t)((tile * 8 + iter) * 1024 + h * 512 + row * 4 + kgs) * 8 + e] = v;
  }
}

// ---------------------------------------------------------------------------
// Fused q/kv projection. 128x128 tile, BK=64 (4 iters). 4 waves = 4 disjoint
// 32-row m-strips x full 128 cols. LDS 32 KB total (single Bs 16 KB + single
// A-image 16 KB) -> 5 blocks/CU resident. Per iter: [bar] issue gll16(B) +
// linear A loads -> cvt+writeA (swizzled image) -> [bar, drains vmcnt] ->
// ds_read frags + MFMA. Conflict-free LDS images (r7 layouts).
// XCD swizzle: 6 n-siblings of one m-tile adjacent on one XCD (A L2 reuse).
// ---------------------------------------------------------------------------
__global__ __launch_bounds__(256, 4) void k_qkv(
    const float* __restrict__ q, const float* __restrict__ kv,
    const bf16* __restrict__ packQ,
    const float* __restrict__ bq, const float* __restrict__ bk,
    const float* __restrict__ bvv,
    bf16* __restrict__ qp, bf16* __restrict__ kp, bf16* __restrict__ vp) {
  __shared__ __align__(16) bf16 Bs[2][128 * 32];   // 16 KB, single buffer
  __shared__ __align__(16) bf16 Alds[128 * 64];    // 16 KB swizzled A-image

  const int g = blockIdx.x, xcd = g & 7, s = g >> 3;
  const int nb = s % 6, mh = s / 6;
  const int m0 = (mh * 8 + xcd) * 128;
  const float* A = (nb < 2) ? q : kv;

  const int tid = threadIdx.x, lane = tid & 63, wave = tid >> 6;
  const int lm = lane & 15, lq = lane >> 4;
  const int swzlq = lq ^ ((lm >> 1) & 3);
  const int mw = wave * 32;

  f32x4 acc[2][8];
#pragma unroll
  for (int t = 0; t < 2; ++t)
#pragma unroll
    for (int nf = 0; nf < 8; ++nf) acc[t][nf] = (f32x4)0.0f;

  const bf16* pbase = packQ + (size_t)nb * 4 * 8192;

  // A staging: thread owns (row = u*16 + tid>>4, 16B f32 chunk c16 = tid&15)
  const int arow = tid >> 4;        // +u*16
  const int ac16 = tid & 15;        // f32 cols ac16*4..+3
  float4 ar[8];                     // one k-slice of A, static-indexed

  auto loadA = [&](int it) {
#pragma unroll
    for (int u = 0; u < 8; ++u) {
      const int row = u * 16 + arow;
      ar[u] = *(const float4*)(A + (size_t)(m0 + row) * 256 + it * 64 + ac16 * 4);
    }
  };
  auto writeA = [&]() {
    const int gsl = ac16 >> 1, half = ac16 & 1;
#pragma unroll
    for (int u = 0; u < 8; ++u) {
      const int row = u * 16 + arow;
      const float4 f = ar[u];
      bf16x4 v;
      v[0] = (bf16)f.x; v[1] = (bf16)f.y; v[2] = (bf16)f.z; v[3] = (bf16)f.w;
      *(bf16x4*)&Alds[row * 64 + ((gsl ^ (row & 7)) << 3) + half * 4] = v;
    }
  };
  auto stageB = [&](int it) {
    const bf16* pit = pbase + it * 8192;
#pragma unroll
    for (int u = 0; u < 4; ++u) {
      const int c = u * 256 + tid;
      bf16* dst = (u < 2) ? &Bs[0][c * 8] : &Bs[1][(c - 512) * 8];
      gll16(pit + c * 8, dst);
    }
  };

#pragma unroll
  for (int i = 0; i < 4; ++i) {
    if (i) __syncthreads();   // bar-a: prior iter's LDS reads complete
    stageB(i);                // gll16 -> Bs (drained at bar-b)
    loadA(i);                 // global -> regs
    writeA();                 // waits its own loads, writes A-image
    __syncthreads();          // bar-b: vmcnt(0) drain (Bs valid) + Alds visible
    // compute on Alds and Bs
#pragma unroll
    for (int ks = 0; ks < 2; ++ks) {
      bf16x8 av[2], bvf[8];
#pragma unroll
      for (int t = 0; t < 2; ++t) {
        const int row = mw + t * 16 + lm;
        av[t] = *(const bf16x8*)&Alds[row * 64 + (((ks * 4 + lq) ^ (lm & 7)) << 3)];
      }
#pragma unroll
      for (int nf = 0; nf < 8; ++nf)
        bvf[nf] = *(const bf16x8*)&Bs[ks][(nf * 16 + lm) * 32 + swzlq * 8];
#pragma unroll
      for (int t = 0; t < 2; ++t)
#pragma unroll
        for (int nf = 0; nf < 8; ++nf)
          acc[t][nf] = __builtin_amdgcn_mfma_f32_16x16x32_bf16(av[t], bvf[nf], acc[t][nf], 0, 0, 0);
    }
  }

  // Epilogue. C layout: col = lane&15, row = (lane>>4)*4 + reg.
  const int ncbase = (nb * 128) & 255;
  bf16* op = (nb < 2) ? qp : (nb < 4) ? kp : vp;
  const float* bp = (nb < 2) ? bq : (nb < 4) ? bk : bvv;
#pragma unroll
  for (int t = 0; t < 2; ++t)
#pragma unroll
    for (int nf = 0; nf < 8; ++nf) {
      const int nc = ncbase + nf * 16 + lm;
      const float bval = bp[nc];
#pragma unroll
      for (int r = 0; r < 4; ++r) {
        const int mg = m0 + mw + t * 16 + lq * 4 + r;
        op[(size_t)mg * 256 + nc] = (bf16)(acc[t][nf][r] + bval);
      }
    }
}

// ---------------------------------------------------------------------------
// Output projection: exact 2-term as K=512 GEMM (8 iters of BK=64: 0-3 hi,
// 4-7 lo; A re-read, L2-hot on 2nd pass). Same r8 single-buffer structure:
// LDS 32 KB -> fully co-resident (1024 blocks = 4/CU <= 5). A (bf16 ao)
// linear loads -> swizzled A-image; B via gll16 from swizzled packO.
// Accumulation order unchanged -> bit-identical out.
// ---------------------------------------------------------------------------
__global__ __launch_bounds__(256, 4) void k_oproj(
    const bf16* __restrict__ ao, const bf16* __restrict__ packO,
    const float* __restrict__ bo, float* __restrict__ out) {
  __shared__ __align__(16) bf16 Bs[2][128 * 32];   // 16 KB, single buffer
  __shared__ __align__(16) bf16 Alds[128 * 64];    // 16 KB swizzled A-image

  const int g = blockIdx.x, xcd = g & 7, s = g >> 3;
  const int nb = s & 1, mh = s >> 1;
  const int m0 = (mh * 8 + xcd) * 128;

  const int tid = threadIdx.x, lane = tid & 63, wave = tid >> 6;
  const int lm = lane & 15, lq = lane >> 4;
  const int swzlq = lq ^ ((lm >> 1) & 3);
  const int mw = wave * 32;

  f32x4 acc[2][8];
#pragma unroll
  for (int t = 0; t < 2; ++t)
#pragma unroll
    for (int nf = 0; nf < 8; ++nf) acc[t][nf] = (f32x4)0.0f;

  const bf16* pbase = packO + (size_t)nb * 8 * 8192;

  // A staging: chunk (row = u*32 + tid>>3, 16B chunk ach = tid&7)
  const int arow = tid >> 3;        // +u*32
  const int ach  = tid & 7;         // 16B chunk within row slice
  bf16x8 arv[4];                    // one k-slice, static-indexed

  auto loadA = [&](int it) {
    const int kA = (it & 3) * 64;   // iters 4-7 re-read same A (hi/lo terms)
#pragma unroll
    for (int u = 0; u < 4; ++u) {
      const int row = u * 32 + arow;
      arv[u] = *(const bf16x8*)(ao + (size_t)(m0 + row) * 256 + kA + ach * 8);
    }
  };
  auto writeA = [&]() {
#pragma unroll
    for (int u = 0; u < 4; ++u) {
      const int row = u * 32 + arow;
      *(bf16x8*)&Alds[row * 64 + ((ach ^ (row & 7)) << 3)] = arv[u];
    }
  };
  auto stageB = [&](int it) {
    const bf16* pit = pbase + (size_t)it * 8192;
#pragma unroll
    for (int u = 0; u < 4; ++u) {
      const int c = u * 256 + tid;
      bf16* dst = (u < 2) ? &Bs[0][c * 8] : &Bs[1][(c - 512) * 8];
      gll16(pit + c * 8, dst);
    }
  };

#pragma unroll
  for (int i = 0; i < 8; ++i) {
    if (i) __syncthreads();   // bar-a
    stageB(i);
    loadA(i);
    writeA();
    __syncthreads();          // bar-b: vmcnt drain + Alds visible
#pragma unroll
    for (int ks = 0; ks < 2; ++ks) {
      bf16x8 av[2], bvf[8];
#pragma unroll
      for (int t = 0; t < 2; ++t) {
        const int row = mw + t * 16 + lm;
        av[t] = *(const bf16x8*)&Alds[row * 64 + (((ks * 4 + lq) ^ (lm & 7)) << 3)];
      }
#pragma unroll
      for (int nf = 0; nf < 8; ++nf)
        bvf[nf] = *(const bf16x8*)&Bs[ks][(nf * 16 + lm) * 32 + swzlq * 8];
#pragma unroll
      for (int t = 0; t < 2; ++t)
#pragma unroll
        for (int nf = 0; nf < 8; ++nf)
          acc[t][nf] = __builtin_amdgcn_mfma_f32_16x16x32_bf16(av[t], bvf[nf], acc[t][nf], 0, 0, 0);
    }
  }

  // Epilogue. C layout: col = lane&15, row = (lane>>4)*4 + reg. f32 out.
#pragma unroll
  for (int t = 0; t < 2; ++t)
#pragma unroll
    for (int nf = 0; nf < 8; ++nf) {
      const int nglob = nb * 128 + nf * 16 + lm;
      const float bval = bo[nglob];
#pragma unroll
      for (int r = 0; r < 4; ++r) {
        const int mg = m0 + mw + t * 16 + lq * 4 + r;
        out[(size_t)mg * 256 + nglob] = acc[t][nf][r] + bval;
      }
    }
}

// ---------------------------------------------------------------------------
// Windowed attention (unchanged).
// ---------------------------------------------------------------------------
__global__ __launch_bounds__(256) void k_attn(
    const bf16* __restrict__ qp, const bf16* __restrict__ kp,
    const bf16* __restrict__ vp, bf16* __restrict__ ao) {
  __shared__ __align__(16) bf16 smem[3 * 64 * 136];
  bf16* Qs = smem;
  bf16* Ks = smem + 64 * 136;
  bf16* Vs = smem + 2 * 64 * 136;
  bf16* Ps = smem;
  bf16* Os = Vs;

  const int tid = threadIdx.x;
  const int lane = tid & 63;
  const int hl = tid >> 6;
  const int bw = blockIdx.x;
  const int b = bw >> 8;
  const int w = bw & 255;
  const int wy = w >> 4, wx = w & 15;
  const int ch0 = blockIdx.y * 128;

#pragma unroll
  for (int i = 0; i < 4; ++i) {
    const int c = i * 256 + tid;
    const int t = c >> 4;
    const int off = (c & 15) * 8;
    const int ty = t >> 3, tx = t & 7;
    const size_t gr = ((size_t)(b * 128 + wy * 8 + ty)) * 128 + wx * 8 + tx;
    const size_t gi = gr * 256 + ch0 + off;
    const int li = t * 136 + off;
    *(uint4*)&Qs[li] = *(const uint4*)&qp[gi];
    *(uint4*)&Ks[li] = *(const uint4*)&kp[gi];
    *(uint4*)&Vs[li] = *(const uint4*)&vp[gi];
  }
  __syncthreads();

  const int chh = hl * 32;
  const int lm = lane & 15;
  const int lq = lane >> 4;

  bf16x8 qa[4], kb[4];
#pragma unroll
  for (int t = 0; t < 4; ++t)
    qa[t] = *(const bf16x8*)&Qs[(t * 16 + lm) * 136 + chh + lq * 8];
#pragma unroll
  for (int t = 0; t < 4; ++t)
    kb[t] = *(const bf16x8*)&Ks[(t * 16 + lm) * 136 + chh + lq * 8];

  f32x4 s[4][4];
#pragma unroll
  for (int i = 0; i < 4; ++i)
#pragma unroll
    for (int j = 0; j < 4; ++j) s[i][j] = (f32x4)0.0f;
#pragma unroll
  for (int i = 0; i < 4; ++i)
#pragma unroll
    for (int j = 0; j < 4; ++j)
      s[i][j] = __builtin_amdgcn_mfma_f32_16x16x32_bf16(qa[i], kb[j], s[i][j], 0, 0, 0);

  const float scale = 0.17677669529663687f;
  float rl[4][4];
#pragma unroll
  for (int mt = 0; mt < 4; ++mt) {
#pragma unroll
    for (int r = 0; r < 4; ++r) {
      float mx = fmaxf(fmaxf(s[mt][0][r], s[mt][1][r]), fmaxf(s[mt][2][r], s[mt][3][r]));
      mx = fmaxf(mx, __shfl_xor(mx, 1));
      mx = fmaxf(mx, __shfl_xor(mx, 2));
      mx = fmaxf(mx, __shfl_xor(mx, 4));
      mx = fmaxf(mx, __shfl_xor(mx, 8));
      float sum = 0.f;
#pragma unroll
      for (int nt = 0; nt < 4; ++nt) {
        const float p = __expf((s[mt][nt][r] - mx) * scale);
        s[mt][nt][r] = p;
        sum += p;
      }
      sum += __shfl_xor(sum, 1);
      sum += __shfl_xor(sum, 2);
      sum += __shfl_xor(sum, 4);
      sum += __shfl_xor(sum, 8);
      rl[mt][r] = 1.0f / sum;
    }
  }

  __syncthreads();

  bf16* Ph = Ps + hl * 4096;
#pragma unroll
  for (int mt = 0; mt < 4; ++mt)
#pragma unroll
    for (int nt = 0; nt < 4; ++nt)
#pragma unroll
      for (int r = 0; r < 4; ++r) {
        const int qrow = mt * 16 + lq * 4 + r;
        const int kcol = nt * 16 + lm;
        Ph[qrow * 64 + (((kcol >> 3) ^ (qrow & 7)) << 3) + (kcol & 7)] = (bf16)s[mt][nt][r];
      }

  f32x4 o[4][2];
#pragma unroll
  for (int i = 0; i < 4; ++i) { o[i][0] = (f32x4)0.0f; o[i][1] = (f32x4)0.0f; }
#pragma unroll
  for (int ks = 0; ks < 2; ++ks) {
    bf16x8 pa[4];
#pragma unroll
    for (int mt = 0; mt < 4; ++mt) {
      const int qrow = mt * 16 + lm;
      const int gsel = ks * 4 + lq;
      pa[mt] = *(const bf16x8*)&Ph[qrow * 64 + ((gsel ^ (qrow & 7)) << 3)];
    }
    bf16x8 vbf[2];
#pragma unroll
    for (int ntd = 0; ntd < 2; ++ntd) {
      const int d = ntd * 16 + lm;
      bf16x8 tv;
#pragma unroll
      for (int j = 0; j < 8; ++j)
        tv[j] = Vs[(ks * 32 + lq * 8 + j) * 136 + chh + d];
      vbf[ntd] = tv;
    }
#pragma unroll
    for (int mt = 0; mt < 4; ++mt)
#pragma unroll
      for (int ntd = 0; ntd < 2; ++ntd)
        o[mt][ntd] = __builtin_amdgcn_mfma_f32_16x16x32_bf16(pa[mt], vbf[ntd], o[mt][ntd], 0, 0, 0);
  }

  __syncthreads();

#pragma unroll
  for (int mt = 0; mt < 4; ++mt)
#pragma unroll
    for (int ntd = 0; ntd < 2; ++ntd)
#pragma unroll
      for (int r = 0; r < 4; ++r) {
        const int qrow = mt * 16 + lq * 4 + r;
        const int d = ntd * 16 + lm;
        Os[qrow * 136 + chh + d] = (bf16)(o[mt][ntd][r] * rl[mt][r]);
      }
  __syncthreads();

#pragma unroll
  for (int i = 0; i < 4; ++i) {
    const int c = i * 256 + tid;
    const int t = c >> 4;
    const int off = (c & 15) * 8;
    const int ty = t >> 3, tx = t & 7;
    const size_t gr = ((size_t)(b * 128 + wy * 8 + ty)) * 128 + wx * 8 + tx;
    *(uint4*)&ao[gr * 256 + ch0 + off] = *(const uint4*)&Os[t * 136 + off];
  }
}

// ---------------------------------------------------------------------------
extern "C" void kernel_launch(void* const* d_in, const int* in_sizes, int n_in,
                              void* d_out, int out_size, void* d_ws, size_t ws_size,
                              hipStream_t stream) {
  const float* q  = (const float*)d_in[0];
  const float* kv = (const float*)d_in[1];
  const float* Wq = (const float*)d_in[2];
  const float* bq = (const float*)d_in[3];
  const float* Wk = (const float*)d_in[4];
  const float* bk = (const float*)d_in[5];
  const float* Wv = (const float*)d_in[6];
  const float* bv = (const float*)d_in[7];
  const float* Wo = (const float*)d_in[8];
  const float* bo = (const float*)d_in[9];
  float* out = (float*)d_out;

  char* ws = (char*)d_ws;
  bf16* packQ = (bf16*)(ws + 0);        // 393216 B
  bf16* packO = (bf16*)(ws + 393216);   // 262144 B
  const size_t PLANE = (size_t)65536 * 256 * 2;
  bf16* qp = (bf16*)(ws + 1048576);
  bf16* kp = (bf16*)(ws + 1048576 + PLANE);
  bf16* vp = (bf16*)(ws + 1048576 + 2 * PLANE);
  bf16* ao = (bf16*)(ws + 1048576 + 3 * PLANE);
  if (ws_size < 1048576 + 4 * PLANE) return;

  k_prep<<<dim3(256, 5), 256, 0, stream>>>(Wq, Wk, Wv, Wo, packQ, packO);
  k_qkv<<<3072, 256, 0, stream>>>(q, kv, packQ, bq, bk, bv, qp, kp, vp);
  k_attn<<<dim3(1024, 2), 256, 0, stream>>>(qp, kp, vp, ao);
  k_oproj<<<1024, 256, 0, stream>>>(ao, packO, bo, out);
}

// Round 6
// 294.765 us; speedup vs baseline: 1.0788x; 1.0788x over previous
//
#include <hip/hip_runtime.h>
#include <hip/hip_bf16.h>

// r9: FULL FUSION. One kernel block per (batch, window): X-stage -> q/k/v
// projections -> windowed attention -> o-projection, all in LDS. Intermediates
// (qp/kp/vp/ao) never touch HBM (was ~256 MB of round-trip traffic across 3
// kernels). Weights stream global->register from fragment-exact packed images
// (1KB/wave-instr coalesced, L2-resident). Per-wave channel-slice ownership
// (2 heads/wave) makes attention barrier-free; 4 barriers total per block.
// LDS 96KB = 3 x 32KB images with reuse: bufA: Xq->qp->ao; bufB: Xkv->vp;
// bufC: kp -> per-wave P-staging band. 1-term bf16 q/kv proj (W hi),
// exact 2-term o-proj (K=512 hi|lo), same accumulation orders as r7/r8.
typedef __bf16 bf16;
typedef __bf16 bf16x8 __attribute__((ext_vector_type(8)));
typedef __bf16 bf16x4 __attribute__((ext_vector_type(4)));
typedef float  f32x4  __attribute__((ext_vector_type(4)));

#define MFMA __builtin_amdgcn_mfma_f32_16x16x32_bf16

// ---------------------------------------------------------------------------
// Weight pack, fragment-exact. Slot = 1KB = one wave B/A-frag load:
//   packW slot (mat, nsl, ks, nf): lane(lq*16+lm) elem e holds
//     W[ks*32 + lq*8 + e][nsl*64 + nf*16 + lm]   (mat 0:Wq 1:Wk 2:Wv, bf16-hi)
//   packO slot (nsl, kss, nf): kss 0-7 = Wo_hi (k=kss*32..), 8-15 = Wo_lo.
// Consumer reads slot base + lane*16B -> perfectly coalesced 1KB.
// ---------------------------------------------------------------------------
__global__ void k_prep(const float* __restrict__ Wq, const float* __restrict__ Wk,
                       const float* __restrict__ Wv, const float* __restrict__ Wo,
                       bf16* __restrict__ packW, bf16* __restrict__ packO) {
  const int n = threadIdx.x;   // 0..255 (output channel)
  const int k = blockIdx.x;    // 0..255 (input channel)
  const int m = blockIdx.y;    // 0:Wq 1:Wk 2:Wv 3:Wo-hi 4:Wo-lo
  const int nsl = n >> 6, nf = (n >> 4) & 3, lm = n & 15;
  const int ks = k >> 5, lq = (k >> 3) & 3, e = k & 7;
  if (m < 3) {
    const float* W = (m == 0) ? Wq : (m == 1) ? Wk : Wv;
    const bf16 v = (bf16)W[k * 256 + n];
    const size_t slot = ((size_t)(m * 4 + nsl) * 8 + ks) * 4 + nf;
    packW[slot * 512 + (lq * 16 + lm) * 8 + e] = v;
  } else {
    const float wv = Wo[k * 256 + n];
    const bf16 hi = (bf16)wv;
    const bf16 v = (m == 3) ? hi : (bf16)(wv - (float)hi);
    const int kss = (m == 3) ? ks : 8 + ks;
    const size_t slot = ((size_t)nsl * 16 + kss) * 4 + nf;
    packO[slot * 512 + (lq * 16 + lm) * 8 + e] = v;
  }
}

// ---------------------------------------------------------------------------
// Fused per-window kernel. Image format (all of bufA/B/C): [64 rows][256 ch]
// bf16, 16B granule g=ch>>3 stored at physical slot g^(row&7) (r7/r8-proven
// conflict-free for b128 fragment reads and b64 writes).
// Wave w owns channel slice [w*64, w*64+64) = heads {2w, 2w+1}.
// MFMA frag convention (verified r2..r8): A/B frag lane(lm,lq): idx=lm,
// k=lq*8+e; D: col=lm (B idx), row=lq*4+r within A block.
// ---------------------------------------------------------------------------
__global__ __launch_bounds__(256, 1) void k_fused(
    const float* __restrict__ q, const float* __restrict__ kv,
    const bf16* __restrict__ packW, const bf16* __restrict__ packO,
    const float* __restrict__ bq, const float* __restrict__ bk,
    const float* __restrict__ bvv, const float* __restrict__ bo,
    float* __restrict__ out) {
  __shared__ __align__(16) bf16 bufA[64 * 256];  // Xq -> qp-img -> ao-img
  __shared__ __align__(16) bf16 bufB[64 * 256];  // Xkv -> vp-img
  __shared__ __align__(16) bf16 bufC[64 * 256];  // kp-img (+ per-wave P band)

  const int tid = threadIdx.x, lane = tid & 63, wave = tid >> 6;
  const int lm = lane & 15, lq = lane >> 4;
  const int bw = blockIdx.x, b = bw >> 8, w = bw & 255;
  const int wy = w >> 4, wx = w & 15;
  const size_t rowbase = ((size_t)(b * 128 + wy * 8)) * 128 + wx * 8;

  // ---- P0: stage Xq, Xkv (f32 global, 1KB/wave-instr) -> bf16 images ----
  {
    const int gx = lane >> 1, half = lane & 1;
#pragma unroll
    for (int i = 0; i < 16; ++i) {
      const int tok = i * 4 + wave;  // one full token row per wave-instr
      const size_t gaddr = (rowbase + (tok >> 3) * 128 + (tok & 7)) * 256 + lane * 4;
      const int la = tok * 256 + ((gx ^ (tok & 7)) << 3) + half * 4;
      float4 f = *(const float4*)(q + gaddr);
      bf16x4 v;
      v[0] = (bf16)f.x; v[1] = (bf16)f.y; v[2] = (bf16)f.z; v[3] = (bf16)f.w;
      *(bf16x4*)&bufA[la] = v;
      f = *(const float4*)(kv + gaddr);
      v[0] = (bf16)f.x; v[1] = (bf16)f.y; v[2] = (bf16)f.z; v[3] = (bf16)f.w;
      *(bf16x4*)&bufB[la] = v;
    }
  }
  __syncthreads();  // bar0: X images complete

  // ---- P1: projections (swapped operands: A=W stream, B=X from LDS) ----
  // D element [n = nsl*64+nf*16+lq*4+r][m = mf*16+lm]; image write is b64.
  auto projAcc = [&](const bf16* Ximg, const bf16* pw, f32x4 (&acc)[4][4]) {
#pragma unroll
    for (int nf = 0; nf < 4; ++nf)
#pragma unroll
      for (int mf = 0; mf < 4; ++mf) acc[nf][mf] = (f32x4)0.0f;
#pragma unroll
    for (int ks = 0; ks < 8; ++ks) {
      bf16x8 wf[4], xf[4];
#pragma unroll
      for (int nf = 0; nf < 4; ++nf)
        wf[nf] = *(const bf16x8*)(pw + ((size_t)(ks * 4 + nf) * 64 + lane) * 8);
#pragma unroll
      for (int mf = 0; mf < 4; ++mf) {
        const int row = mf * 16 + lm;
        xf[mf] = *(const bf16x8*)&Ximg[row * 256 + (((ks * 4 + lq) ^ (row & 7)) << 3)];
      }
#pragma unroll
      for (int nf = 0; nf < 4; ++nf)
#pragma unroll
        for (int mf = 0; mf < 4; ++mf)
          acc[nf][mf] = MFMA(wf[nf], xf[mf], acc[nf][mf], 0, 0, 0);
    }
  };
  auto writeProj = [&](bf16* img, const float* bias, f32x4 (&acc)[4][4]) {
#pragma unroll
    for (int nf = 0; nf < 4; ++nf) {
      const int n0 = wave * 64 + nf * 16 + lq * 4;
      const float4 bb = *(const float4*)(bias + n0);
      const int gsl = wave * 8 + nf * 2 + (lq >> 1);  // logical granule of n0
#pragma unroll
      for (int mf = 0; mf < 4; ++mf) {
        const int m = mf * 16 + lm;
        bf16x4 v;
        v[0] = (bf16)(acc[nf][mf][0] + bb.x);
        v[1] = (bf16)(acc[nf][mf][1] + bb.y);
        v[2] = (bf16)(acc[nf][mf][2] + bb.z);
        v[3] = (bf16)(acc[nf][mf][3] + bb.w);
        *(bf16x4*)&img[m * 256 + ((gsl ^ (m & 7)) << 3) + (lq & 1) * 4] = v;
      }
    }
  };

  {
    f32x4 pacc[4][4];
    projAcc(bufA, packW + (size_t)(0 * 4 + wave) * 16384, pacc);
    __syncthreads();                 // bar1: all waves done reading Xq
    writeProj(bufA, bq, pacc);       // qp over Xq (own granule band)
    projAcc(bufB, packW + (size_t)(1 * 4 + wave) * 16384, pacc);
    writeProj(bufC, bk, pacc);       // kp to fresh bufC (own band, self-read)
    projAcc(bufB, packW + (size_t)(2 * 4 + wave) * 16384, pacc);
    __syncthreads();                 // bar2: all waves done reading Xkv
    writeProj(bufB, bvv, pacc);      // vp over Xkv (own band)
  }

  // ---- P2: attention, fully per-wave (2 heads), no barriers ----
  const float scale = 0.17677669529663687f;
  f32x4 s[2][4][4];
#pragma unroll
  for (int h = 0; h < 2; ++h) {      // QK^T both heads BEFORE K band reuse
    const int h4 = wave * 8 + h * 4; // logical granule base of head's 32 ch
    bf16x8 qa[4], kb[4];
#pragma unroll
    for (int t = 0; t < 4; ++t) {
      const int row = t * 16 + lm;
      const int go = ((h4 + lq) ^ (row & 7)) << 3;
      qa[t] = *(const bf16x8*)&bufA[row * 256 + go];
      kb[t] = *(const bf16x8*)&bufC[row * 256 + go];
    }
#pragma unroll
    for (int i = 0; i < 4; ++i)
#pragma unroll
      for (int j = 0; j < 4; ++j) {
        s[h][i][j] = (f32x4)0.0f;
        s[h][i][j] = MFMA(qa[i], kb[j], s[h][i][j], 0, 0, 0);
      }
  }

#pragma unroll
  for (int h = 0; h < 2; ++h) {
    // softmax (k_attn-verbatim): rows = qtok(lq*4+r), cols = ktok(nf*16+lm)
    float rl[4][4];
#pragma unroll
    for (int mt = 0; mt < 4; ++mt)
#pragma unroll
      for (int r = 0; r < 4; ++r) {
        float mx = fmaxf(fmaxf(s[h][mt][0][r], s[h][mt][1][r]),
                         fmaxf(s[h][mt][2][r], s[h][mt][3][r]));
        mx = fmaxf(mx, __shfl_xor(mx, 1));
        mx = fmaxf(mx, __shfl_xor(mx, 2));
        mx = fmaxf(mx, __shfl_xor(mx, 4));
        mx = fmaxf(mx, __shfl_xor(mx, 8));
        float sum = 0.f;
#pragma unroll
        for (int nt = 0; nt < 4; ++nt) {
          const float p = __expf((s[h][mt][nt][r] - mx) * scale);
          s[h][mt][nt][r] = p;
          sum += p;
        }
        sum += __shfl_xor(sum, 1);
        sum += __shfl_xor(sum, 2);
        sum += __shfl_xor(sum, 4);
        sum += __shfl_xor(sum, 8);
        rl[mt][r] = 1.0f / sum;
      }

    // P staging into own bufC band (K dead: both heads' QK done)
#pragma unroll
    for (int mt = 0; mt < 4; ++mt)
#pragma unroll
      for (int nt = 0; nt < 4; ++nt)
#pragma unroll
        for (int r = 0; r < 4; ++r) {
          const int qrow = mt * 16 + lq * 4 + r;
          const int kcol = nt * 16 + lm;
          bufC[qrow * 256 + ((wave * 8 + ((kcol >> 3) ^ (qrow & 7))) << 3) + (kcol & 7)] =
              (bf16)s[h][mt][nt][r];
        }

    // PV: o[qtok][d], d = head ch + ntd*16+lm
    f32x4 o[4][2];
#pragma unroll
    for (int i = 0; i < 4; ++i) { o[i][0] = (f32x4)0.0f; o[i][1] = (f32x4)0.0f; }
#pragma unroll
    for (int ks2 = 0; ks2 < 2; ++ks2) {
      bf16x8 pa[4];
#pragma unroll
      for (int mt = 0; mt < 4; ++mt) {
        const int qrow = mt * 16 + lm;
        const int gsel = ks2 * 4 + lq;
        pa[mt] = *(const bf16x8*)&bufC[qrow * 256 + ((wave * 8 + (gsel ^ (qrow & 7))) << 3)];
      }
      bf16x8 vb[2];
#pragma unroll
      for (int ntd = 0; ntd < 2; ++ntd) {
        const int gv = wave * 8 + h * 4 + ntd * 2 + (lm >> 3);
        bf16x8 tv;
#pragma unroll
        for (int j = 0; j < 8; ++j) {
          const int tok = ks2 * 32 + lq * 8 + j;
          tv[j] = bufB[tok * 256 + ((gv ^ (tok & 7)) << 3) + (lm & 7)];
        }
        vb[ntd] = tv;
      }
#pragma unroll
      for (int mt = 0; mt < 4; ++mt)
#pragma unroll
        for (int ntd = 0; ntd < 2; ++ntd)
          o[mt][ntd] = MFMA(pa[mt], vb[ntd], o[mt][ntd], 0, 0, 0);
    }

    // rescale + write o into own bufA band (Q dead after QK reads)
#pragma unroll
    for (int mt = 0; mt < 4; ++mt)
#pragma unroll
      for (int ntd = 0; ntd < 2; ++ntd) {
        const int gv = wave * 8 + h * 4 + ntd * 2 + (lm >> 3);
#pragma unroll
        for (int r = 0; r < 4; ++r) {
          const int tok = mt * 16 + lq * 4 + r;
          bufA[tok * 256 + ((gv ^ (tok & 7)) << 3) + (lm & 7)] =
              (bf16)(o[mt][ntd][r] * rl[mt][r]);
        }
      }
  }
  __syncthreads();  // bar3: ao image complete (oproj reads all bands)

  // ---- P3: o-projection, exact 2-term K=512 (ks 0-7 hi, 8-15 lo) ----
  {
    f32x4 oacc[4][4];  // [mf][nf]: [tok = mf*16+lq*4+r][n = wave*64+nf*16+lm]
#pragma unroll
    for (int mf = 0; mf < 4; ++mf)
#pragma unroll
      for (int nf = 0; nf < 4; ++nf) oacc[mf][nf] = (f32x4)0.0f;
    const bf16* po = packO + (size_t)wave * 32768;
#pragma unroll
    for (int ks = 0; ks < 16; ++ks) {
      bf16x8 af[4], bf_[4];
#pragma unroll
      for (int mf = 0; mf < 4; ++mf) {
        const int row = mf * 16 + lm;
        af[mf] = *(const bf16x8*)&bufA[row * 256 + ((((ks & 7) * 4 + lq) ^ (row & 7)) << 3)];
      }
#pragma unroll
      for (int nf = 0; nf < 4; ++nf)
        bf_[nf] = *(const bf16x8*)(po + ((size_t)(ks * 4 + nf) * 64 + lane) * 8);
#pragma unroll
      for (int mf = 0; mf < 4; ++mf)
#pragma unroll
        for (int nf = 0; nf < 4; ++nf)
          oacc[mf][nf] = MFMA(af[mf], bf_[nf], oacc[mf][nf], 0, 0, 0);
    }
    // epilogue: f32 out + bias
#pragma unroll
    for (int nf = 0; nf < 4; ++nf) {
      const int n = wave * 64 + nf * 16 + lm;
      const float bval = bo[n];
#pragma unroll
      for (int mf = 0; mf < 4; ++mf)
#pragma unroll
        for (int r = 0; r < 4; ++r) {
          const int tok = mf * 16 + lq * 4 + r;
          const size_t gr = rowbase + (tok >> 3) * 128 + (tok & 7);
          out[gr * 256 + n] = oacc[mf][nf][r] + bval;
        }
    }
  }
}

// ---------------------------------------------------------------------------
extern "C" void kernel_launch(void* const* d_in, const int* in_sizes, int n_in,
                              void* d_out, int out_size, void* d_ws, size_t ws_size,
                              hipStream_t stream) {
  const float* q  = (const float*)d_in[0];
  const float* kv = (const float*)d_in[1];
  const float* Wq = (const float*)d_in[2];
  const float* bq = (const float*)d_in[3];
  const float* Wk = (const float*)d_in[4];
  const float* bk = (const float*)d_in[5];
  const float* Wv = (const float*)d_in[6];
  const float* bv = (const float*)d_in[7];
  const float* Wo = (const float*)d_in[8];
  const float* bo = (const float*)d_in[9];
  float* out = (float*)d_out;

  char* ws = (char*)d_ws;
  bf16* packW = (bf16*)(ws + 0);        // 384 KB: 3 mats x 4 nsl x 8 ks x 4 nf x 1KB
  bf16* packO = (bf16*)(ws + 393216);   // 256 KB: 4 nsl x 16 kss x 4 nf x 1KB
  if (ws_size < 655360) return;

  k_prep<<<dim3(256, 5), 256, 0, stream>>>(Wq, Wk, Wv, Wo, packW, packO);
  k_fused<<<1024, 256, 0, stream>>>(q, kv, packW, packO, bq, bk, bv, bo, out);
}